// Round 6
// baseline (29.857 us; speedup 1.0000x reference)
//
#include <hip/hip_runtime.h>

// Channelwise Sorensen-Dice over (1,3,96,256,256) fp32; each channel is a
// contiguous 6,291,456-float block. Per-channel sum(x*t), sum(x*x), sum(t*t);
// loss = sum_c -2*num/max(den,eps).
//
// R6: R5 (contention-free partials) + 2-deep double-buffered LDS-DMA pipeline
// with counted vmcnt(2) — a wave never fully drains its load queue inside the
// loop, so its bytes-in-flight stay nonzero through the whole sweep.
#define NCH 3
#define PER_CH 6291456
#define THREADS 256
#define WPB 4                       // waves per block
#define GRIDX 512                   // blocks per channel
#define NWX (GRIDX * WPB)           // 2048 waves per channel
#define CHUNK 256                   // floats per array per chunk = 1 KB = one gload16
#define NCHUNK 12                   // PER_CH / (CHUNK * NWX) == 12 exactly
#define EPS 1e-6f

__device__ __forceinline__ void gload16(const float* g, float* l) {
    // dwordx4 direct global->LDS: lane i's 16B land at l + i*16.
    __builtin_amdgcn_global_load_lds(
        (__attribute__((address_space(1))) void*)g,
        (__attribute__((address_space(3))) void*)l,
        16, 0, 0);
}

// partial layout in d_ws: partial[(ch*3+k)*GRIDX + bx], k=0:xt 1:xx 2:tt
__global__ void __launch_bounds__(256)
dice_partial_kernel(const float* __restrict__ x, const float* __restrict__ t,
                    float* __restrict__ partial) {
    __shared__ __align__(16) float lx[WPB][2][CHUNK];
    __shared__ __align__(16) float lt[WPB][2][CHUNK];
    __shared__ float red[3][WPB];

    const int lane = threadIdx.x & 63;
    const int wave = threadIdx.x >> 6;
    const int ch = blockIdx.y;
    const int gwx = blockIdx.x * WPB + wave;
    const size_t ch_base = (size_t)ch * PER_CH + (size_t)lane * 4;

    float sxt = 0.f, sxx = 0.f, stt = 0.f;

    // Prologue: fill buffer 0 with chunk 0.
    {
        const size_t g0 = ch_base + (size_t)gwx * CHUNK;
        gload16(x + g0, &lx[wave][0][0]);
        gload16(t + g0, &lt[wave][0][0]);
    }

#pragma unroll
    for (int j = 0; j < NCHUNK; ++j) {
        if (j < NCHUNK - 1) {
            const size_t gn = ch_base + (size_t)(gwx + (j + 1) * NWX) * CHUNK;
            gload16(x + gn, &lx[wave][(j + 1) & 1][0]);
            gload16(t + gn, &lt[wave][(j + 1) & 1][0]);
            // chunk j's 2 loads done; chunk j+1's 2 stay in flight
            asm volatile("s_waitcnt vmcnt(2)" ::: "memory");
        } else {
            asm volatile("s_waitcnt vmcnt(0)" ::: "memory");
        }
        float4 xv = *reinterpret_cast<const float4*>(&lx[wave][j & 1][lane * 4]);
        float4 tv = *reinterpret_cast<const float4*>(&lt[wave][j & 1][lane * 4]);
        sxt += xv.x * tv.x + xv.y * tv.y + xv.z * tv.z + xv.w * tv.w;
        sxx += xv.x * xv.x + xv.y * xv.y + xv.z * xv.z + xv.w * xv.w;
        stt += tv.x * tv.x + tv.y * tv.y + tv.z * tv.z + tv.w * tv.w;
    }

    // Wave-64 butterfly reduction
    for (int off = 32; off > 0; off >>= 1) {
        sxt += __shfl_xor(sxt, off, 64);
        sxx += __shfl_xor(sxx, off, 64);
        stt += __shfl_xor(stt, off, 64);
    }

    // Cross-wave reduction (4 waves), then contention-free plain stores.
    if (lane == 0) {
        red[0][wave] = sxt;
        red[1][wave] = sxx;
        red[2][wave] = stt;
    }
    __syncthreads();
    if (threadIdx.x == 0) {
        float bxt = red[0][0] + red[0][1] + red[0][2] + red[0][3];
        float bxx = red[1][0] + red[1][1] + red[1][2] + red[1][3];
        float btt = red[2][0] + red[2][1] + red[2][2] + red[2][3];
        partial[(ch * 3 + 0) * GRIDX + blockIdx.x] = bxt;
        partial[(ch * 3 + 1) * GRIDX + blockIdx.x] = bxx;
        partial[(ch * 3 + 2) * GRIDX + blockIdx.x] = btt;
    }
}

// 9 waves (576 threads): wave w reduces row w of partial[9][GRIDX].
__global__ void __launch_bounds__(576)
dice_final_kernel(const float* __restrict__ partial, float* __restrict__ out) {
    __shared__ float red[9];
    const int w = threadIdx.x >> 6;     // 0..8
    const int lane = threadIdx.x & 63;

    float s = 0.f;
    const float* row = partial + w * GRIDX;
#pragma unroll
    for (int i = 0; i < GRIDX / 64; ++i) s += row[lane + i * 64];
    for (int off = 32; off > 0; off >>= 1) s += __shfl_xor(s, off, 64);
    if (lane == 0) red[w] = s;
    __syncthreads();

    if (threadIdx.x == 0) {
        float loss = 0.f;
        for (int c = 0; c < NCH; ++c) {
            float num = red[c * 3 + 0];
            float den = red[c * 3 + 1] + red[c * 3 + 2];
            loss += -2.f * (num / fmaxf(den, EPS));
        }
        out[0] = loss;
    }
}

extern "C" void kernel_launch(void* const* d_in, const int* in_sizes, int n_in,
                              void* d_out, int out_size, void* d_ws, size_t ws_size,
                              hipStream_t stream) {
    const float* x = (const float*)d_in[0];
    const float* t = (const float*)d_in[1];
    float* partial = (float*)d_ws;      // 9*GRIDX floats = 18 KB, fully overwritten each call
    float* out = (float*)d_out;

    dim3 grid(GRIDX, NCH);
    dice_partial_kernel<<<grid, THREADS, 0, stream>>>(x, t, partial);
    dice_final_kernel<<<1, 576, 0, stream>>>(partial, out);
}